// Round 10
// baseline (77.479 us; speedup 1.0000x reference)
//
#include <hip/hip_runtime.h>

// Trilinear warp (SpatialTransformer): vol [B=2,D=160,H=192,W=160,C=2] f32,
// flow [B,D,H,W,3] f32 ('ij'). Output f32, same shape as vol.
//
// R9 (74.5us): branchless LDS path + deferred wave-uniform fixup. Profile:
// ~60% VALU-busy, LDS pipe ~28us, HBM floor 33us. R10 shaves both pipes:
//  - z-pair ds_read2_b64: 16 -> 8 LDS instrs/thread, half the gather addrs;
//    volume z-top folded into weights (R5-proven, <=1 ulp).
//  - integer floor/clamp path (med3) — same float results, fewer VALU.

constexpr int Bb = 2, Dd = 160, Hh = 192, Ww = 160;
constexpr int HW  = Hh * Ww;          // 30720
constexpr int VOX = Dd * HW;          // 4,915,200 voxels per batch

constexpr int TD = 8,  TH = 16, TW = 16;   // output tile (2048 voxels)
constexpr int RD = TD + 8;                 // 16  staged region (halo 4)
constexpr int RH = TH + 8;                 // 24
constexpr int RW = TW + 8;                 // 24  (extent always even)
constexpr int RWP = 26;                    // padded LDS row stride (float2)
constexpr int QROW = RW / 2;               // 12 float4 quads per row
constexpr int NQ = RD * RH * QROW;         // 4608 staged quads
constexpr int ND = Dd / TD, NH = Hh / TH, NW = Ww / TW;   // 20, 12, 10
constexpr int NBLK = Bb * ND * NH * NW;                   // 4800
constexpr int BLOCK = 1024;                // 16 waves; 2 voxels per thread
constexpr size_t LDS_BYTES = (size_t)RD * RH * RWP * sizeof(float2);  // 79872

// Exact reference math + global gathers — rare out-of-halo lanes only
// (P ~ 1.9e-4/voxel). Identical formulas/op-order to the reference.
__device__ __forceinline__ void sample_global(const float2* __restrict__ v2,
                                              int d, int h, int w,
                                              float fx, float fy, float fz,
                                              float& oxv, float& oyv)
{
    const float mx = (float)(Dd - 1), my = (float)(Hh - 1), mz = (float)(Ww - 1);
    const float lxf = (float)d + fx;
    const float lyf = (float)h + fy;
    const float lzf = (float)w + fz;

    const float l0x = fminf(fmaxf(floorf(lxf), 0.0f), mx);
    const float l0y = fminf(fmaxf(floorf(lyf), 0.0f), my);
    const float l0z = fminf(fmaxf(floorf(lzf), 0.0f), mz);
    const float l1x = fminf(l0x + 1.0f, mx);
    const float l1y = fminf(l0y + 1.0f, my);
    const float l1z = fminf(l0z + 1.0f, mz);

    const float d1x = l1x - lxf, d0x = 1.0f - d1x;
    const float d1y = l1y - lyf, d0y = 1.0f - d1y;
    const float d1z = l1z - lzf, d0z = 1.0f - d1z;

    const int i0x = (int)l0x, i1x = (int)l1x;
    const int i0y = (int)l0y, i1y = (int)l1y;
    const int i0z = (int)l0z, i1z = (int)l1z;

    const int rx0 = i0x * HW, rx1 = i1x * HW;
    const int ry0 = i0y * Ww, ry1 = i1y * Ww;
    const float2 c000 = v2[rx0 + ry0 + i0z], c001 = v2[rx0 + ry0 + i1z];
    const float2 c010 = v2[rx0 + ry1 + i0z], c011 = v2[rx0 + ry1 + i1z];
    const float2 c100 = v2[rx1 + ry0 + i0z], c101 = v2[rx1 + ry0 + i1z];
    const float2 c110 = v2[rx1 + ry1 + i0z], c111 = v2[rx1 + ry1 + i1z];

    const float w000 = d1x * d1y * d1z, w001 = d1x * d1y * d0z;
    const float w010 = d1x * d0y * d1z, w011 = d1x * d0y * d0z;
    const float w100 = d0x * d1y * d1z, w101 = d0x * d1y * d0z;
    const float w110 = d0x * d0y * d1z, w111 = d0x * d0y * d0z;

    oxv = w000 * c000.x;
    oyv = w000 * c000.y;
    oxv = fmaf(w001, c001.x, oxv);  oyv = fmaf(w001, c001.y, oyv);
    oxv = fmaf(w010, c010.x, oxv);  oyv = fmaf(w010, c010.y, oyv);
    oxv = fmaf(w011, c011.x, oxv);  oyv = fmaf(w011, c011.y, oyv);
    oxv = fmaf(w100, c100.x, oxv);  oyv = fmaf(w100, c100.y, oyv);
    oxv = fmaf(w101, c101.x, oxv);  oyv = fmaf(w101, c101.y, oyv);
    oxv = fmaf(w110, c110.x, oxv);  oyv = fmaf(w110, c110.y, oyv);
    oxv = fmaf(w111, c111.x, oxv);  oyv = fmaf(w111, c111.y, oyv);
}

__global__ __launch_bounds__(BLOCK, 8)   // 8 waves/EU => VGPR<=64 => 2 blocks/CU
void SpatialTransformer_44418551776013_kernel(const float* __restrict__ vol,
                                              const float* __restrict__ flow,
                                              float* __restrict__ out)
{
    extern __shared__ float2 sv[];   // [RD][RH][RWP]
    const int tid = threadIdx.x;

    // bijective XCD swizzle (NBLK % 8 == 0): neighboring tiles share halo
    // lines on one XCD's L2. Validated: FETCH 222 -> 132 MB.
    constexpr int CPX = NBLK / 8;    // 600
    int bid = (int)(blockIdx.x % 8) * CPX + (int)(blockIdx.x / 8);

    const int bw = bid % NW;  bid /= NW;
    const int bh = bid % NH;  bid /= NH;
    const int bd = bid % ND;
    const int b  = bid / ND;
    const int d0 = bd * TD, h0 = bh * TH, w0 = bw * TW;

    // staged region = clip(tile +- 4); block-uniform -> SGPRs
    const int ox = max(0, d0 - 4), oy = max(0, h0 - 4), oz = max(0, w0 - 4);
    const int ex = min(Dd - 1, d0 + TD + 3) - ox + 1;   // <= RD
    const int ey = min(Hh - 1, h0 + TH + 3) - oy + 1;   // <= RH
    const int ez = min(Ww - 1, w0 + TW + 3) - oz + 1;   // <= RW, even
    const int qz = ez >> 1;
    const int bx1 = ox + ex, by1 = oy + ey, bz1 = oz + ez;   // ok-test bounds

    // compute mapping: (tdg, th, tw); thread owns td = tdg and tdg+4
    const int tw  = tid & 15;
    const int th  = (tid >> 4) & 15;
    const int tdg = tid >> 8;            // 0..3
    const int h = h0 + th, w = w0 + tw;
    const int gidx1 = ((b * Dd + d0 + tdg) * Hh + h) * Ww + w;
    const int gidx2 = gidx1 + 4 * HW;
    const int dA = d0 + tdg, dB = dA + 4;

    // flow loads first: independent of staging, in flight during it
    const float fx1 = flow[(size_t)gidx1 * 3 + 0];
    const float fy1 = flow[(size_t)gidx1 * 3 + 1];
    const float fz1 = flow[(size_t)gidx1 * 3 + 2];
    const float fx2 = flow[(size_t)gidx2 * 3 + 0];
    const float fy2 = flow[(size_t)gidx2 * 3 + 1];
    const float fz2 = flow[(size_t)gidx2 * 3 + 2];

    const float2* __restrict__ v2 =
        reinterpret_cast<const float2*>(vol) + (size_t)b * VOX;

    // ---- stage region into LDS (R8-proven: one float4 live, no spill) ----
    #pragma unroll 1
    for (int i = tid; i < NQ; i += BLOCK) {   // 4-5 iterations
        int lq = i % QROW;                    // compile-time divisors
        const int t  = i / QROW;
        int ly = t % RH;
        int lx = t / RH;
        const int s = (lx * RH + ly) * RWP + 2 * lq;
        lx = min(lx, ex - 1);  ly = min(ly, ey - 1);  lq = min(lq, qz - 1);
        const float4 v = *reinterpret_cast<const float4*>(
            v2 + ((size_t)(ox + lx) * HW + (oy + ly) * Ww + oz + 2 * lq));
        *reinterpret_cast<float4*>(&sv[s]) = v;
    }
    __syncthreads();

    // Branchless LDS sample with z-paired reads. ok-lanes exact; not-ok
    // lanes read clamped (safe) garbage overwritten by the deferred fixup.
    auto sample_lds = [&](int d, float fx, float fy, float fz,
                          float& oxv, float& oyv, bool& ok) {
        const float lxf = (float)d + fx;
        const float lyf = (float)h + fy;
        const float lzf = (float)w + fz;

        // integer floor path: (float)i equals the reference's clipped floor
        // exactly (all indices <= 191 are exact in f32).
        const int fx_i = __float2int_rd(lxf);
        const int fy_i = __float2int_rd(lyf);
        const int fz_i = __float2int_rd(lzf);
        const int i0x = min(max(fx_i, 0), Dd - 1);   // v_med3_i32
        const int i0y = min(max(fy_i, 0), Hh - 1);
        const int i0z = min(max(fz_i, 0), Ww - 1);
        const int i1x = min(i0x + 1, Dd - 1);
        const int i1y = min(i0y + 1, Hh - 1);
        const int i1z = min(i0z + 1, Ww - 1);

        const float d1x = (float)i1x - lxf, d0x = 1.0f - d1x;
        const float d1y = (float)i1y - lyf, d0y = 1.0f - d1y;
        const float d1z = (float)i1z - lzf, d0z = 1.0f - d1z;

        ok = (i0x >= ox) & (i1x < bx1) &
             (i0y >= oy) & (i1y < by1) &
             (i0z >= oz) & (i1z < bz1);

        // clamped region-local x/y coords (no-ops for ok lanes)
        const int c0x = min(max(i0x - ox, 0), ex - 1);
        const int c1x = min(max(i1x - ox, 0), ex - 1);
        const int c0y = min(max(i0y - oy, 0), ey - 1);
        const int c1y = min(max(i1y - oy, 0), ey - 1);

        // z-pair: read [zb, zb+1]; volume z-top puts all weight on zb+1.
        // ok & !ztop => a0z <= ez-2 (since a1z = a0z+1 <= ez-1): med3 no-op.
        // ok &  ztop => region touches volume top, a0z = ez-1, zb = ez-2,
        //               pair = {garbage(w=0), vol[W-1](w=d1z+d0z)}.
        const bool  zt  = (i0z == Ww - 1);
        const int   zb  = min(max(i0z - oz - (zt ? 1 : 0), 0), ez - 2);
        const float wzl = zt ? 0.0f : d1z;
        const float wzh = zt ? (d1z + d0z) : d0z;

        const int r00 = (c0x * RH + c0y) * RWP + zb;
        const int r01 = (c0x * RH + c1y) * RWP + zb;
        const int r10 = (c1x * RH + c0y) * RWP + zb;
        const int r11 = (c1x * RH + c1y) * RWP + zb;

        // paired reads: same base, +8B neighbor -> ds_read2_b64
        const float2 p00l = sv[r00], p00h = sv[r00 + 1];
        const float2 p01l = sv[r01], p01h = sv[r01 + 1];
        const float2 p10l = sv[r10], p10h = sv[r10 + 1];
        const float2 p11l = sv[r11], p11h = sv[r11 + 1];

        const float xy00 = d1x * d1y, xy01 = d1x * d0y;
        const float xy10 = d0x * d1y, xy11 = d0x * d0y;
        const float w00l = xy00 * wzl, w00h = xy00 * wzh;
        const float w01l = xy01 * wzl, w01h = xy01 * wzh;
        const float w10l = xy10 * wzl, w10h = xy10 * wzh;
        const float w11l = xy11 * wzl, w11h = xy11 * wzh;

        oxv = w00l * p00l.x;
        oyv = w00l * p00l.y;
        oxv = fmaf(w00h, p00h.x, oxv);  oyv = fmaf(w00h, p00h.y, oyv);
        oxv = fmaf(w01l, p01l.x, oxv);  oyv = fmaf(w01l, p01l.y, oyv);
        oxv = fmaf(w01h, p01h.x, oxv);  oyv = fmaf(w01h, p01h.y, oyv);
        oxv = fmaf(w10l, p10l.x, oxv);  oyv = fmaf(w10l, p10l.y, oyv);
        oxv = fmaf(w10h, p10h.x, oxv);  oyv = fmaf(w10h, p10h.y, oyv);
        oxv = fmaf(w11l, p11l.x, oxv);  oyv = fmaf(w11l, p11l.y, oyv);
        oxv = fmaf(w11h, p11h.x, oxv);  oyv = fmaf(w11h, p11h.y, oyv);
    };

    // ---- both samples: one straight-line block, no divergent CFG ----
    float o1x, o1y, o2x, o2y;
    bool ok1, ok2;
    sample_lds(dA, fx1, fy1, fz1, o1x, o1y, ok1);
    sample_lds(dB, fx2, fy2, fz2, o2x, o2y, ok2);

    // ---- deferred rare fixup (wave-uniform skip ~97% of waves) ----
    if (!__all(ok1 && ok2)) {
        if (!ok1) sample_global(v2, dA, h, w, fx1, fy1, fz1, o1x, o1y);
        if (!ok2) sample_global(v2, dB, h, w, fx2, fy2, fz2, o2x, o2y);
    }

    reinterpret_cast<float2*>(out)[gidx1] = make_float2(o1x, o1y);
    reinterpret_cast<float2*>(out)[gidx2] = make_float2(o2x, o2y);
}

extern "C" void kernel_launch(void* const* d_in, const int* in_sizes, int n_in,
                              void* d_out, int out_size, void* d_ws, size_t ws_size,
                              hipStream_t stream)
{
    const float* vol  = (const float*)d_in[0];   // [2,160,192,160,2] f32
    const float* flow = (const float*)d_in[1];   // [2,160,192,160,3] f32
    float* out = (float*)d_out;                  // [2,160,192,160,2] f32

    SpatialTransformer_44418551776013_kernel<<<NBLK, BLOCK, LDS_BYTES, stream>>>(vol, flow, out);
}

// Round 11
// 71.545 us; speedup vs baseline: 1.0829x; 1.0829x over previous
//
#include <hip/hip_runtime.h>

// Trilinear warp (SpatialTransformer): vol [B=2,D=160,H=192,W=160,C=2] f32,
// flow [B,D,H,W,3] f32 ('ij'). Output f32, same shape as vol.
//
// R10 lesson: ds_read2_b64 pairing RAISED bank conflicts 9.99M->13.97M (net
// -4%); integer med3 coord math saved ~3us VALU (validated, bit-identical).
// R11: R9's 8x independent ds_read_b64 pattern + med3 math + w-paired
// voxels (thread owns w,w+1): flow = float4+float2 (6 loads -> 2), output =
// one 16B float4 store (2 -> 1). Tile/staging/swizzle/fixup unchanged.

constexpr int Bb = 2, Dd = 160, Hh = 192, Ww = 160;
constexpr int HW  = Hh * Ww;          // 30720
constexpr int VOX = Dd * HW;          // 4,915,200 voxels per batch

constexpr int TD = 8,  TH = 16, TW = 16;   // output tile (2048 voxels)
constexpr int RD = TD + 8;                 // 16  staged region (halo 4)
constexpr int RH = TH + 8;                 // 24
constexpr int RW = TW + 8;                 // 24  (extent always even)
constexpr int RWP = 26;                    // padded LDS row stride (float2)
constexpr int QROW = RW / 2;               // 12 float4 quads per row
constexpr int NQ = RD * RH * QROW;         // 4608 staged quads
constexpr int ND = Dd / TD, NH = Hh / TH, NW = Ww / TW;   // 20, 12, 10
constexpr int NBLK = Bb * ND * NH * NW;                   // 4800
constexpr int BLOCK = 1024;                // 16 waves; 2 voxels per thread
constexpr size_t LDS_BYTES = (size_t)RD * RH * RWP * sizeof(float2);  // 79872

// Exact reference math + global gathers — rare out-of-halo lanes only
// (P ~ 1.9e-4/voxel). Identical formulas/op-order to the reference.
__device__ __forceinline__ void sample_global(const float2* __restrict__ v2,
                                              int d, int h, int w,
                                              float fx, float fy, float fz,
                                              float& oxv, float& oyv)
{
    const float mx = (float)(Dd - 1), my = (float)(Hh - 1), mz = (float)(Ww - 1);
    const float lxf = (float)d + fx;
    const float lyf = (float)h + fy;
    const float lzf = (float)w + fz;

    const float l0x = fminf(fmaxf(floorf(lxf), 0.0f), mx);
    const float l0y = fminf(fmaxf(floorf(lyf), 0.0f), my);
    const float l0z = fminf(fmaxf(floorf(lzf), 0.0f), mz);
    const float l1x = fminf(l0x + 1.0f, mx);
    const float l1y = fminf(l0y + 1.0f, my);
    const float l1z = fminf(l0z + 1.0f, mz);

    const float d1x = l1x - lxf, d0x = 1.0f - d1x;
    const float d1y = l1y - lyf, d0y = 1.0f - d1y;
    const float d1z = l1z - lzf, d0z = 1.0f - d1z;

    const int i0x = (int)l0x, i1x = (int)l1x;
    const int i0y = (int)l0y, i1y = (int)l1y;
    const int i0z = (int)l0z, i1z = (int)l1z;

    const int rx0 = i0x * HW, rx1 = i1x * HW;
    const int ry0 = i0y * Ww, ry1 = i1y * Ww;
    const float2 c000 = v2[rx0 + ry0 + i0z], c001 = v2[rx0 + ry0 + i1z];
    const float2 c010 = v2[rx0 + ry1 + i0z], c011 = v2[rx0 + ry1 + i1z];
    const float2 c100 = v2[rx1 + ry0 + i0z], c101 = v2[rx1 + ry0 + i1z];
    const float2 c110 = v2[rx1 + ry1 + i0z], c111 = v2[rx1 + ry1 + i1z];

    const float w000 = d1x * d1y * d1z, w001 = d1x * d1y * d0z;
    const float w010 = d1x * d0y * d1z, w011 = d1x * d0y * d0z;
    const float w100 = d0x * d1y * d1z, w101 = d0x * d1y * d0z;
    const float w110 = d0x * d0y * d1z, w111 = d0x * d0y * d0z;

    oxv = w000 * c000.x;
    oyv = w000 * c000.y;
    oxv = fmaf(w001, c001.x, oxv);  oyv = fmaf(w001, c001.y, oyv);
    oxv = fmaf(w010, c010.x, oxv);  oyv = fmaf(w010, c010.y, oyv);
    oxv = fmaf(w011, c011.x, oxv);  oyv = fmaf(w011, c011.y, oyv);
    oxv = fmaf(w100, c100.x, oxv);  oyv = fmaf(w100, c100.y, oyv);
    oxv = fmaf(w101, c101.x, oxv);  oyv = fmaf(w101, c101.y, oyv);
    oxv = fmaf(w110, c110.x, oxv);  oyv = fmaf(w110, c110.y, oyv);
    oxv = fmaf(w111, c111.x, oxv);  oyv = fmaf(w111, c111.y, oyv);
}

__global__ __launch_bounds__(BLOCK, 8)   // 8 waves/EU => VGPR<=64 => 2 blocks/CU
void SpatialTransformer_44418551776013_kernel(const float* __restrict__ vol,
                                              const float* __restrict__ flow,
                                              float* __restrict__ out)
{
    extern __shared__ float2 sv[];   // [RD][RH][RWP]
    const int tid = threadIdx.x;

    // bijective XCD swizzle (NBLK % 8 == 0): neighboring tiles share halo
    // lines on one XCD's L2. Validated: FETCH 222 -> 132 MB.
    constexpr int CPX = NBLK / 8;    // 600
    int bid = (int)(blockIdx.x % 8) * CPX + (int)(blockIdx.x / 8);

    const int bw = bid % NW;  bid /= NW;
    const int bh = bid % NH;  bid /= NH;
    const int bd = bid % ND;
    const int b  = bid / ND;
    const int d0 = bd * TD, h0 = bh * TH, w0 = bw * TW;

    // staged region = clip(tile +- 4); block-uniform -> SGPRs
    const int ox = max(0, d0 - 4), oy = max(0, h0 - 4), oz = max(0, w0 - 4);
    const int ex = min(Dd - 1, d0 + TD + 3) - ox + 1;   // <= RD
    const int ey = min(Hh - 1, h0 + TH + 3) - oy + 1;   // <= RH
    const int ez = min(Ww - 1, w0 + TW + 3) - oz + 1;   // <= RW, even
    const int qz = ez >> 1;
    const int bx1 = ox + ex, by1 = oy + ey, bz1 = oz + ez;   // ok-test bounds

    // compute mapping: (td, th, tw2); thread owns voxels (d,h,w) & (d,h,w+1)
    const int tw2 = tid & 7;             // w-pair index 0..7
    const int th  = (tid >> 3) & 15;     // 0..15
    const int td  = tid >> 7;            // 0..7
    const int h = h0 + th;
    const int w = w0 + 2 * tw2;
    const int d = d0 + td;
    const int gidx = ((b * Dd + d) * Hh + h) * Ww + w;   // even

    // flow for BOTH voxels = 6 contiguous floats: float4 + float2
    // (byte offset 12*gidx, gidx even -> 8B-aligned; OK per R5 evidence).
    const float4 fA = *reinterpret_cast<const float4*>(flow + (size_t)gidx * 3);
    const float2 fB = *reinterpret_cast<const float2*>(flow + (size_t)gidx * 3 + 4);
    // voxel 1: (fA.x, fA.y, fA.z)   voxel 2: (fA.w, fB.x, fB.y)

    const float2* __restrict__ v2 =
        reinterpret_cast<const float2*>(vol) + (size_t)b * VOX;

    // ---- stage region into LDS (R8-proven: one float4 live, no spill) ----
    #pragma unroll 1
    for (int i = tid; i < NQ; i += BLOCK) {   // 4-5 iterations
        int lq = i % QROW;                    // compile-time divisors
        const int t  = i / QROW;
        int ly = t % RH;
        int lx = t / RH;
        const int s = (lx * RH + ly) * RWP + 2 * lq;
        lx = min(lx, ex - 1);  ly = min(ly, ey - 1);  lq = min(lq, qz - 1);
        const float4 v = *reinterpret_cast<const float4*>(
            v2 + ((size_t)(ox + lx) * HW + (oy + ly) * Ww + oz + 2 * lq));
        *reinterpret_cast<float4*>(&sv[s]) = v;
    }
    __syncthreads();

    // Branchless LDS sample (R9 read pattern: 8 independent ds_read_b64;
    // R10-validated integer med3 coord path). ok-lanes exact; not-ok lanes
    // read clamped garbage overwritten by the deferred fixup.
    auto sample_lds = [&](int dd, int ww, float fx, float fy, float fz,
                          float& oxv, float& oyv, bool& ok) {
        const float lxf = (float)dd + fx;
        const float lyf = (float)h  + fy;
        const float lzf = (float)ww + fz;

        // integer floor path: (float)i equals the reference's clipped floor
        // exactly (all indices <= 191 are exact in f32).
        const int i0x = min(max(__float2int_rd(lxf), 0), Dd - 1);  // v_med3
        const int i0y = min(max(__float2int_rd(lyf), 0), Hh - 1);
        const int i0z = min(max(__float2int_rd(lzf), 0), Ww - 1);
        const int i1x = min(i0x + 1, Dd - 1);
        const int i1y = min(i0y + 1, Hh - 1);
        const int i1z = min(i0z + 1, Ww - 1);

        const float d1x = (float)i1x - lxf, d0x = 1.0f - d1x;
        const float d1y = (float)i1y - lyf, d0y = 1.0f - d1y;
        const float d1z = (float)i1z - lzf, d0z = 1.0f - d1z;

        ok = (i0x >= ox) & (i1x < bx1) &
             (i0y >= oy) & (i1y < by1) &
             (i0z >= oz) & (i1z < bz1);

        // clamped region-local coords (no-ops for ok lanes)
        const int c0x = min(max(i0x - ox, 0), ex - 1);
        const int c1x = min(max(i1x - ox, 0), ex - 1);
        const int c0y = min(max(i0y - oy, 0), ey - 1);
        const int c1y = min(max(i1y - oy, 0), ey - 1);
        const int c0z = min(max(i0z - oz, 0), ez - 1);
        const int c1z = min(max(i1z - oz, 0), ez - 1);

        const int r00 = (c0x * RH + c0y) * RWP;
        const int r01 = (c0x * RH + c1y) * RWP;
        const int r10 = (c1x * RH + c0y) * RWP;
        const int r11 = (c1x * RH + c1y) * RWP;
        const float2 c000 = sv[r00 + c0z], c001 = sv[r00 + c1z];
        const float2 c010 = sv[r01 + c0z], c011 = sv[r01 + c1z];
        const float2 c100 = sv[r10 + c0z], c101 = sv[r10 + c1z];
        const float2 c110 = sv[r11 + c0z], c111 = sv[r11 + c1z];

        const float xy00 = d1x * d1y, xy01 = d1x * d0y;
        const float xy10 = d0x * d1y, xy11 = d0x * d0y;
        const float w000 = xy00 * d1z, w001 = xy00 * d0z;
        const float w010 = xy01 * d1z, w011 = xy01 * d0z;
        const float w100 = xy10 * d1z, w101 = xy10 * d0z;
        const float w110 = xy11 * d1z, w111 = xy11 * d0z;

        oxv = w000 * c000.x;
        oyv = w000 * c000.y;
        oxv = fmaf(w001, c001.x, oxv);  oyv = fmaf(w001, c001.y, oyv);
        oxv = fmaf(w010, c010.x, oxv);  oyv = fmaf(w010, c010.y, oyv);
        oxv = fmaf(w011, c011.x, oxv);  oyv = fmaf(w011, c011.y, oyv);
        oxv = fmaf(w100, c100.x, oxv);  oyv = fmaf(w100, c100.y, oyv);
        oxv = fmaf(w101, c101.x, oxv);  oyv = fmaf(w101, c101.y, oyv);
        oxv = fmaf(w110, c110.x, oxv);  oyv = fmaf(w110, c110.y, oyv);
        oxv = fmaf(w111, c111.x, oxv);  oyv = fmaf(w111, c111.y, oyv);
    };

    // ---- both samples: one straight-line block, no divergent CFG ----
    float o1x, o1y, o2x, o2y;
    bool ok1, ok2;
    sample_lds(d, w,     fA.x, fA.y, fA.z, o1x, o1y, ok1);
    sample_lds(d, w + 1, fA.w, fB.x, fB.y, o2x, o2y, ok2);

    // ---- deferred rare fixup (wave-uniform skip ~97% of waves) ----
    if (!__all(ok1 && ok2)) {
        if (!ok1) sample_global(v2, d, h, w,     fA.x, fA.y, fA.z, o1x, o1y);
        if (!ok2) sample_global(v2, d, h, w + 1, fA.w, fB.x, fB.y, o2x, o2y);
    }

    // both voxels' outputs are adjacent float2s -> one 16B-aligned store
    *reinterpret_cast<float4*>(reinterpret_cast<float2*>(out) + gidx) =
        make_float4(o1x, o1y, o2x, o2y);
}

extern "C" void kernel_launch(void* const* d_in, const int* in_sizes, int n_in,
                              void* d_out, int out_size, void* d_ws, size_t ws_size,
                              hipStream_t stream)
{
    const float* vol  = (const float*)d_in[0];   // [2,160,192,160,2] f32
    const float* flow = (const float*)d_in[1];   // [2,160,192,160,3] f32
    float* out = (float*)d_out;                  // [2,160,192,160,2] f32

    SpatialTransformer_44418551776013_kernel<<<NBLK, BLOCK, LDS_BYTES, stream>>>(vol, flow, out);
}

// Round 12
// 65.843 us; speedup vs baseline: 1.1767x; 1.0866x over previous
//
#include <hip/hip_runtime.h>

// Trilinear warp (SpatialTransformer): vol [B=2,D=160,H=192,W=160,C=2] f32,
// flow [B,D,H,W,3] f32 ('ij'). Output f32, same shape as vol.
//
// R11 (71.5us): LDS tile+halo4, 1024-thr, 2 blocks/CU, branchless samples,
// med3 int coords, w-paired voxels. R12: staging via global_load_lds DMA
// (width=16) — removes the VGPR round-trip, ~45 VALU/thread of staging
// address work off the critical path, and all ds_write_b128 (~7us LDS
// pipe). Requires LINEAR LDS (no pad): RWP 26 -> 24, slot = i*16B, which
// matches the HW's wave-uniform-base + lane*16 rule exactly.

constexpr int Bb = 2, Dd = 160, Hh = 192, Ww = 160;
constexpr int HW  = Hh * Ww;          // 30720
constexpr int VOX = Dd * HW;          // 4,915,200 voxels per batch

constexpr int TD = 8,  TH = 16, TW = 16;   // output tile (2048 voxels)
constexpr int RD = TD + 8;                 // 16  staged region (halo 4)
constexpr int RH = TH + 8;                 // 24
constexpr int RW = TW + 8;                 // 24  (extent always even)
constexpr int RWP = 24;                    // UNPADDED row stride (float2) — linear for DMA
constexpr int QROW = RW / 2;               // 12 float4 quads per row
constexpr int NQ = RD * RH * QROW;         // 4608 staged quads (i*16B linear)
constexpr int ND = Dd / TD, NH = Hh / TH, NW = Ww / TW;   // 20, 12, 10
constexpr int NBLK = Bb * ND * NH * NW;                   // 4800
constexpr int BLOCK = 1024;                // 16 waves; 2 voxels per thread
constexpr size_t LDS_BYTES = (size_t)NQ * 16;             // 73728 B

// Exact reference math + global gathers — rare out-of-halo lanes only
// (P ~ 1.9e-4/voxel). Identical formulas/op-order to the reference.
__device__ __forceinline__ void sample_global(const float2* __restrict__ v2,
                                              int d, int h, int w,
                                              float fx, float fy, float fz,
                                              float& oxv, float& oyv)
{
    const float mx = (float)(Dd - 1), my = (float)(Hh - 1), mz = (float)(Ww - 1);
    const float lxf = (float)d + fx;
    const float lyf = (float)h + fy;
    const float lzf = (float)w + fz;

    const float l0x = fminf(fmaxf(floorf(lxf), 0.0f), mx);
    const float l0y = fminf(fmaxf(floorf(lyf), 0.0f), my);
    const float l0z = fminf(fmaxf(floorf(lzf), 0.0f), mz);
    const float l1x = fminf(l0x + 1.0f, mx);
    const float l1y = fminf(l0y + 1.0f, my);
    const float l1z = fminf(l0z + 1.0f, mz);

    const float d1x = l1x - lxf, d0x = 1.0f - d1x;
    const float d1y = l1y - lyf, d0y = 1.0f - d1y;
    const float d1z = l1z - lzf, d0z = 1.0f - d1z;

    const int i0x = (int)l0x, i1x = (int)l1x;
    const int i0y = (int)l0y, i1y = (int)l1y;
    const int i0z = (int)l0z, i1z = (int)l1z;

    const int rx0 = i0x * HW, rx1 = i1x * HW;
    const int ry0 = i0y * Ww, ry1 = i1y * Ww;
    const float2 c000 = v2[rx0 + ry0 + i0z], c001 = v2[rx0 + ry0 + i1z];
    const float2 c010 = v2[rx0 + ry1 + i0z], c011 = v2[rx0 + ry1 + i1z];
    const float2 c100 = v2[rx1 + ry0 + i0z], c101 = v2[rx1 + ry0 + i1z];
    const float2 c110 = v2[rx1 + ry1 + i0z], c111 = v2[rx1 + ry1 + i1z];

    const float w000 = d1x * d1y * d1z, w001 = d1x * d1y * d0z;
    const float w010 = d1x * d0y * d1z, w011 = d1x * d0y * d0z;
    const float w100 = d0x * d1y * d1z, w101 = d0x * d1y * d0z;
    const float w110 = d0x * d0y * d1z, w111 = d0x * d0y * d0z;

    oxv = w000 * c000.x;
    oyv = w000 * c000.y;
    oxv = fmaf(w001, c001.x, oxv);  oyv = fmaf(w001, c001.y, oyv);
    oxv = fmaf(w010, c010.x, oxv);  oyv = fmaf(w010, c010.y, oyv);
    oxv = fmaf(w011, c011.x, oxv);  oyv = fmaf(w011, c011.y, oyv);
    oxv = fmaf(w100, c100.x, oxv);  oyv = fmaf(w100, c100.y, oyv);
    oxv = fmaf(w101, c101.x, oxv);  oyv = fmaf(w101, c101.y, oyv);
    oxv = fmaf(w110, c110.x, oxv);  oyv = fmaf(w110, c110.y, oyv);
    oxv = fmaf(w111, c111.x, oxv);  oyv = fmaf(w111, c111.y, oyv);
}

__global__ __launch_bounds__(BLOCK, 8)   // 8 waves/EU => VGPR<=64 => 2 blocks/CU
void SpatialTransformer_44418551776013_kernel(const float* __restrict__ vol,
                                              const float* __restrict__ flow,
                                              float* __restrict__ out)
{
    extern __shared__ float2 sv[];   // [RD][RH][RWP], RWP=24 => fully linear
    const int tid = threadIdx.x;

    // bijective XCD swizzle (NBLK % 8 == 0): neighboring tiles share halo
    // lines on one XCD's L2. Validated: FETCH 222 -> 132 MB.
    constexpr int CPX = NBLK / 8;    // 600
    int bid = (int)(blockIdx.x % 8) * CPX + (int)(blockIdx.x / 8);

    const int bw = bid % NW;  bid /= NW;
    const int bh = bid % NH;  bid /= NH;
    const int bd = bid % ND;
    const int b  = bid / ND;
    const int d0 = bd * TD, h0 = bh * TH, w0 = bw * TW;

    // staged region = clip(tile +- 4); block-uniform -> SGPRs
    const int ox = max(0, d0 - 4), oy = max(0, h0 - 4), oz = max(0, w0 - 4);
    const int ex = min(Dd - 1, d0 + TD + 3) - ox + 1;   // <= RD
    const int ey = min(Hh - 1, h0 + TH + 3) - oy + 1;   // <= RH
    const int ez = min(Ww - 1, w0 + TW + 3) - oz + 1;   // <= RW, even
    const int qz = ez >> 1;
    const int bx1 = ox + ex, by1 = oy + ey, bz1 = oz + ez;   // ok-test bounds

    // compute mapping: (td, th, tw2); thread owns voxels (d,h,w) & (d,h,w+1)
    const int tw2 = tid & 7;             // w-pair index 0..7
    const int th  = (tid >> 3) & 15;     // 0..15
    const int td  = tid >> 7;            // 0..7
    const int h = h0 + th;
    const int w = w0 + 2 * tw2;
    const int d = d0 + td;
    const int gidx = ((b * Dd + d) * Hh + h) * Ww + w;   // even

    // flow for BOTH voxels = 6 contiguous floats: float4 + float2
    const float4 fA = *reinterpret_cast<const float4*>(flow + (size_t)gidx * 3);
    const float2 fB = *reinterpret_cast<const float2*>(flow + (size_t)gidx * 3 + 4);
    // voxel 1: (fA.x, fA.y, fA.z)   voxel 2: (fA.w, fB.x, fB.y)

    const float2* __restrict__ v2 =
        reinterpret_cast<const float2*>(vol) + (size_t)b * VOX;

    // ---- stage region via global_load_lds DMA (16B per lane) ----
    // LDS dest: slot(i) = i*16B, and within a wave i = wavebase + lane, so
    // dest = uniform_base + lane*16 — exactly the HW rule (m104/m173).
    // Tail: NQ=4608, boundary at tid 512 is wave-aligned -> uniform branch.
    // Global src clamped into valid extent (edge dup lines -> L2 hits).
    #pragma unroll 1
    for (int k = 0; k < 5; ++k) {
        const int i = tid + k * BLOCK;
        if (i < NQ) {
            int lq = i % QROW;               // compile-time divisors
            const int t  = i / QROW;
            int ly = t % RH;
            int lx = t / RH;
            lx = min(lx, ex - 1);  ly = min(ly, ey - 1);  lq = min(lq, qz - 1);
            const float2* src =
                v2 + ((size_t)(ox + lx) * HW + (oy + ly) * Ww + oz + 2 * lq);
            __builtin_amdgcn_global_load_lds(
                (const __attribute__((address_space(1))) void*)src,
                (__attribute__((address_space(3))) void*)(sv + (size_t)2 * i),
                16, 0, 0);
        }
    }
    __syncthreads();   // compiler drains vmcnt(0) before s_barrier

    // Branchless LDS sample (8 independent ds_read_b64 — R10 showed pairing
    // raises conflicts; med3 int coord path — R10-validated bit-identical).
    auto sample_lds = [&](int dd, int ww, float fx, float fy, float fz,
                          float& oxv, float& oyv, bool& ok) {
        const float lxf = (float)dd + fx;
        const float lyf = (float)h  + fy;
        const float lzf = (float)ww + fz;

        const int i0x = min(max(__float2int_rd(lxf), 0), Dd - 1);  // v_med3
        const int i0y = min(max(__float2int_rd(lyf), 0), Hh - 1);
        const int i0z = min(max(__float2int_rd(lzf), 0), Ww - 1);
        const int i1x = min(i0x + 1, Dd - 1);
        const int i1y = min(i0y + 1, Hh - 1);
        const int i1z = min(i0z + 1, Ww - 1);

        const float d1x = (float)i1x - lxf, d0x = 1.0f - d1x;
        const float d1y = (float)i1y - lyf, d0y = 1.0f - d1y;
        const float d1z = (float)i1z - lzf, d0z = 1.0f - d1z;

        ok = (i0x >= ox) & (i1x < bx1) &
             (i0y >= oy) & (i1y < by1) &
             (i0z >= oz) & (i1z < bz1);

        // clamped region-local coords (no-ops for ok lanes)
        const int c0x = min(max(i0x - ox, 0), ex - 1);
        const int c1x = min(max(i1x - ox, 0), ex - 1);
        const int c0y = min(max(i0y - oy, 0), ey - 1);
        const int c1y = min(max(i1y - oy, 0), ey - 1);
        const int c0z = min(max(i0z - oz, 0), ez - 1);
        const int c1z = min(max(i1z - oz, 0), ez - 1);

        const int r00 = (c0x * RH + c0y) * RWP;
        const int r01 = (c0x * RH + c1y) * RWP;
        const int r10 = (c1x * RH + c0y) * RWP;
        const int r11 = (c1x * RH + c1y) * RWP;
        const float2 c000 = sv[r00 + c0z], c001 = sv[r00 + c1z];
        const float2 c010 = sv[r01 + c0z], c011 = sv[r01 + c1z];
        const float2 c100 = sv[r10 + c0z], c101 = sv[r10 + c1z];
        const float2 c110 = sv[r11 + c0z], c111 = sv[r11 + c1z];

        const float xy00 = d1x * d1y, xy01 = d1x * d0y;
        const float xy10 = d0x * d1y, xy11 = d0x * d0y;
        const float w000 = xy00 * d1z, w001 = xy00 * d0z;
        const float w010 = xy01 * d1z, w011 = xy01 * d0z;
        const float w100 = xy10 * d1z, w101 = xy10 * d0z;
        const float w110 = xy11 * d1z, w111 = xy11 * d0z;

        oxv = w000 * c000.x;
        oyv = w000 * c000.y;
        oxv = fmaf(w001, c001.x, oxv);  oyv = fmaf(w001, c001.y, oyv);
        oxv = fmaf(w010, c010.x, oxv);  oyv = fmaf(w010, c010.y, oyv);
        oxv = fmaf(w011, c011.x, oxv);  oyv = fmaf(w011, c011.y, oyv);
        oxv = fmaf(w100, c100.x, oxv);  oyv = fmaf(w100, c100.y, oyv);
        oxv = fmaf(w101, c101.x, oxv);  oyv = fmaf(w101, c101.y, oyv);
        oxv = fmaf(w110, c110.x, oxv);  oyv = fmaf(w110, c110.y, oyv);
        oxv = fmaf(w111, c111.x, oxv);  oyv = fmaf(w111, c111.y, oyv);
    };

    // ---- both samples: one straight-line block, no divergent CFG ----
    float o1x, o1y, o2x, o2y;
    bool ok1, ok2;
    sample_lds(d, w,     fA.x, fA.y, fA.z, o1x, o1y, ok1);
    sample_lds(d, w + 1, fA.w, fB.x, fB.y, o2x, o2y, ok2);

    // ---- deferred rare fixup (wave-uniform skip ~97% of waves) ----
    if (!__all(ok1 && ok2)) {
        if (!ok1) sample_global(v2, d, h, w,     fA.x, fA.y, fA.z, o1x, o1y);
        if (!ok2) sample_global(v2, d, h, w + 1, fA.w, fB.x, fB.y, o2x, o2y);
    }

    // both voxels' outputs are adjacent float2s -> one 16B-aligned store
    *reinterpret_cast<float4*>(reinterpret_cast<float2*>(out) + gidx) =
        make_float4(o1x, o1y, o2x, o2y);
}

extern "C" void kernel_launch(void* const* d_in, const int* in_sizes, int n_in,
                              void* d_out, int out_size, void* d_ws, size_t ws_size,
                              hipStream_t stream)
{
    const float* vol  = (const float*)d_in[0];   // [2,160,192,160,2] f32
    const float* flow = (const float*)d_in[1];   // [2,160,192,160,3] f32
    float* out = (float*)d_out;                  // [2,160,192,160,2] f32

    SpatialTransformer_44418551776013_kernel<<<NBLK, BLOCK, LDS_BYTES, stream>>>(vol, flow, out);
}